// Round 1
// baseline (3648.866 us; speedup 1.0000x reference)
//
#include <hip/hip_runtime.h>
#include <hip/hip_cooperative_groups.h>

namespace cg = cooperative_groups;

static constexpr int HID  = 4096;  // hidden size
static constexpr int SEQL = 40;
static constexpr int OUTN = 128;

// ---------- fp32 -> bf16 (RNE) conversion ----------
__device__ __forceinline__ unsigned short f2bf(float f) {
    unsigned u = __float_as_uint(f);
    unsigned r = (u + 0x7fffu + ((u >> 16) & 1u)) >> 16;
    return (unsigned short)r;
}

__global__ void convert_w_kernel(const float* __restrict__ w,
                                 ushort4* __restrict__ o, int n4) {
    int stride = gridDim.x * blockDim.x;
    const float4* w4 = (const float4*)w;
    for (int i = blockIdx.x * blockDim.x + threadIdx.x; i < n4; i += stride) {
        float4 v = w4[i];
        ushort4 r;
        r.x = f2bf(v.x); r.y = f2bf(v.y); r.z = f2bf(v.z); r.w = f2bf(v.w);
        o[i] = r;
    }
}

// ---------- helpers ----------
__device__ __forceinline__ float bflo(unsigned u) { return __uint_as_float(u << 16); }
__device__ __forceinline__ float bfhi(unsigned u) { return __uint_as_float(u & 0xffff0000u); }

__device__ __forceinline__ float dot8_bf(uint4 w, float4 ha, float4 hb, float acc) {
    acc = fmaf(bflo(w.x), ha.x, acc);
    acc = fmaf(bfhi(w.x), ha.y, acc);
    acc = fmaf(bflo(w.y), ha.z, acc);
    acc = fmaf(bfhi(w.y), ha.w, acc);
    acc = fmaf(bflo(w.z), hb.x, acc);
    acc = fmaf(bfhi(w.z), hb.y, acc);
    acc = fmaf(bflo(w.w), hb.z, acc);
    acc = fmaf(bfhi(w.w), hb.w, acc);
    return acc;
}

__device__ __forceinline__ float dot8_f32(float4 wa, float4 wb, float4 ha, float4 hb, float acc) {
    acc = fmaf(wa.x, ha.x, acc);
    acc = fmaf(wa.y, ha.y, acc);
    acc = fmaf(wa.z, ha.z, acc);
    acc = fmaf(wa.w, ha.w, acc);
    acc = fmaf(wb.x, hb.x, acc);
    acc = fmaf(wb.y, hb.y, acc);
    acc = fmaf(wb.z, hb.z, acc);
    acc = fmaf(wb.w, hb.w, acc);
    return acc;
}

__device__ __forceinline__ float sigm(float x) { return 1.0f / (1.0f + expf(-x)); }

// ---------- persistent cooperative LSTM ----------
// grid: 256 blocks x 1024 threads = 4096 waves = one wave per hidden unit.
// Each wave owns gate rows {j, H+j, 2H+j, 3H+j} and keeps c[j] in registers.
// One grid.sync() per timestep (h double-buffered in d_ws).
template <bool BF16>
__global__ void __launch_bounds__(1024, 4)
lstm_kernel(const float* __restrict__ x,
            const float* __restrict__ w_ih,
            const float* __restrict__ b_ih,
            const float* __restrict__ b_hh,
            const void*  __restrict__ whh,
            const float* __restrict__ dense_w,
            const float* __restrict__ dense_b,
            float* __restrict__ h0,
            float* __restrict__ h1,
            float* __restrict__ out) {
    cg::grid_group grid = cg::this_grid();
    const int lane = threadIdx.x & 63;
    const int wave = (blockIdx.x << 4) | (threadIdx.x >> 6);  // 0..4095
    const int j = wave;  // hidden unit owned by this wave

    // Per-gate constants for unit j (i, f, g, o rows)
    float wih[4], bb[4];
#pragma unroll
    for (int g = 0; g < 4; ++g) {
        int r = g * HID + j;
        wih[g] = w_ih[r];
        bb[g]  = b_ih[r] + b_hh[r];
    }

    const uint4*  wr_bf[4];
    const float4* wr_f[4];
#pragma unroll
    for (int g = 0; g < 4; ++g) {
        size_t rowoff = (size_t)(g * HID + j) * HID;
        wr_bf[g] = (const uint4*)((const unsigned short*)whh + rowoff);
        wr_f[g]  = (const float4*)((const float*)whh + rowoff);
    }

    if (lane == 0) h0[j] = 0.0f;
    float c = 0.0f;
    grid.sync();

    for (int t = 0; t < SEQL; ++t) {
        const float4* hr = (const float4*)((t & 1) ? h1 : h0);
        float*        hw = (t & 1) ? h0 : h1;
        float xt = x[t];
        float acc0 = 0.f, acc1 = 0.f, acc2 = 0.f, acc3 = 0.f;
#pragma unroll
        for (int it = 0; it < 8; ++it) {
            float4 ha = hr[it * 128 + lane * 2];
            float4 hb = hr[it * 128 + lane * 2 + 1];
            if constexpr (BF16) {
                uint4 w0 = wr_bf[0][it * 64 + lane];
                uint4 w1 = wr_bf[1][it * 64 + lane];
                uint4 w2 = wr_bf[2][it * 64 + lane];
                uint4 w3 = wr_bf[3][it * 64 + lane];
                acc0 = dot8_bf(w0, ha, hb, acc0);
                acc1 = dot8_bf(w1, ha, hb, acc1);
                acc2 = dot8_bf(w2, ha, hb, acc2);
                acc3 = dot8_bf(w3, ha, hb, acc3);
            } else {
                int i0 = it * 128 + lane * 2;
                acc0 = dot8_f32(wr_f[0][i0], wr_f[0][i0 + 1], ha, hb, acc0);
                acc1 = dot8_f32(wr_f[1][i0], wr_f[1][i0 + 1], ha, hb, acc1);
                acc2 = dot8_f32(wr_f[2][i0], wr_f[2][i0 + 1], ha, hb, acc2);
                acc3 = dot8_f32(wr_f[3][i0], wr_f[3][i0 + 1], ha, hb, acc3);
            }
        }
        // 64-lane butterfly reduction (all lanes end with the full sum)
#pragma unroll
        for (int off = 32; off; off >>= 1) {
            acc0 += __shfl_xor(acc0, off, 64);
            acc1 += __shfl_xor(acc1, off, 64);
            acc2 += __shfl_xor(acc2, off, 64);
            acc3 += __shfl_xor(acc3, off, 64);
        }
        float gi = acc0 + wih[0] * xt + bb[0];
        float gf = acc1 + wih[1] * xt + bb[1];
        float gg = acc2 + wih[2] * xt + bb[2];
        float go = acc3 + wih[3] * xt + bb[3];
        c = sigm(gf) * c + sigm(gi) * tanhf(gg);
        float hn = sigm(go) * tanhf(c);
        if (lane == 0) hw[j] = hn;
        grid.sync();
    }

    // SEQL=40 even -> last write (t=39) went to h0.
    if (wave < OUTN) {
        const float4* hv  = (const float4*)h0;
        const float4* dwr = (const float4*)(dense_w + (size_t)wave * HID);
        float acc = 0.f;
#pragma unroll
        for (int it = 0; it < 8; ++it) {
            int i0 = it * 128 + lane * 2;
            float4 ha = hv[i0];
            float4 hb = hv[i0 + 1];
            acc = dot8_f32(dwr[i0], dwr[i0 + 1], ha, hb, acc);
        }
#pragma unroll
        for (int off = 32; off; off >>= 1) acc += __shfl_xor(acc, off, 64);
        if (lane == 0) out[wave] = acc + dense_b[wave];
    }
}

extern "C" void kernel_launch(void* const* d_in, const int* in_sizes, int n_in,
                              void* d_out, int out_size, void* d_ws, size_t ws_size,
                              hipStream_t stream) {
    const float* x       = (const float*)d_in[0];
    const float* w_ih    = (const float*)d_in[1];
    const float* w_hh    = (const float*)d_in[2];
    const float* b_ih    = (const float*)d_in[3];
    const float* b_hh    = (const float*)d_in[4];
    const float* dense_w = (const float*)d_in[5];
    const float* dense_b = (const float*)d_in[6];
    float* out = (float*)d_out;

    // ws layout: [h0: HID f32][h1: HID f32][w_hh as bf16: 4*HID*HID ushort]
    float* h0 = (float*)d_ws;
    float* h1 = h0 + HID;

    size_t need = (size_t)2 * HID * sizeof(float) +
                  (size_t)4 * HID * HID * sizeof(unsigned short);
    bool use_bf16 = ws_size >= need;

    if (use_bf16) {
        unsigned short* wbf = (unsigned short*)(h1 + HID);
        int n4 = 4 * HID * HID / 4;
        convert_w_kernel<<<4096, 256, 0, stream>>>(w_hh, (ushort4*)wbf, n4);

        const void* wptr = (const void*)wbf;
        void* args[] = {(void*)&x, (void*)&w_ih, (void*)&b_ih, (void*)&b_hh,
                        (void*)&wptr, (void*)&dense_w, (void*)&dense_b,
                        (void*)&h0, (void*)&h1, (void*)&out};
        void* fn = (void*)lstm_kernel<true>;
        hipLaunchCooperativeKernel(fn, dim3(256), dim3(1024), args, 0, stream);
    } else {
        const void* wptr = (const void*)w_hh;
        void* args[] = {(void*)&x, (void*)&w_ih, (void*)&b_ih, (void*)&b_hh,
                        (void*)&wptr, (void*)&dense_w, (void*)&dense_b,
                        (void*)&h0, (void*)&h1, (void*)&out};
        void* fn = (void*)lstm_kernel<false>;
        hipLaunchCooperativeKernel(fn, dim3(256), dim3(1024), args, 0, stream);
    }
}

// Round 3
// 3598.359 us; speedup vs baseline: 1.0140x; 1.0140x over previous
//
#include <hip/hip_runtime.h>
#include <hip/hip_cooperative_groups.h>

namespace cg = cooperative_groups;

static constexpr int HID  = 4096;  // hidden size
static constexpr int SEQL = 40;
static constexpr int OUTN = 128;

// ---------- fp32 -> bf16 (RNE) conversion ----------
__device__ __forceinline__ unsigned f2bf(float f) {
    unsigned u = __float_as_uint(f);
    return (u + 0x7fffu + ((u >> 16) & 1u)) >> 16;
}

// Packs 8 floats -> 8 bf16 (one uint4 store, 16B) per iteration.
__global__ void convert_w_kernel(const float4* __restrict__ w,
                                 uint4* __restrict__ o, int n8) {
    int stride = gridDim.x * blockDim.x;
    for (int i = blockIdx.x * blockDim.x + threadIdx.x; i < n8; i += stride) {
        float4 a = w[2 * i];
        float4 b = w[2 * i + 1];
        uint4 r;
        r.x = f2bf(a.x) | (f2bf(a.y) << 16);
        r.y = f2bf(a.z) | (f2bf(a.w) << 16);
        r.z = f2bf(b.x) | (f2bf(b.y) << 16);
        r.w = f2bf(b.z) | (f2bf(b.w) << 16);
        o[i] = r;
    }
}

// ---------- helpers ----------
__device__ __forceinline__ float bflo(unsigned u) { return __uint_as_float(u << 16); }
__device__ __forceinline__ float bfhi(unsigned u) { return __uint_as_float(u & 0xffff0000u); }

__device__ __forceinline__ float dot8_bf(uint4 w, float4 ha, float4 hb, float acc) {
    acc = fmaf(bflo(w.x), ha.x, acc);
    acc = fmaf(bfhi(w.x), ha.y, acc);
    acc = fmaf(bflo(w.y), ha.z, acc);
    acc = fmaf(bfhi(w.y), ha.w, acc);
    acc = fmaf(bflo(w.z), hb.x, acc);
    acc = fmaf(bfhi(w.z), hb.y, acc);
    acc = fmaf(bflo(w.w), hb.z, acc);
    acc = fmaf(bfhi(w.w), hb.w, acc);
    return acc;
}

__device__ __forceinline__ float dot8_f32(float4 wa, float4 wb, float4 ha, float4 hb, float acc) {
    acc = fmaf(wa.x, ha.x, acc);
    acc = fmaf(wa.y, ha.y, acc);
    acc = fmaf(wa.z, ha.z, acc);
    acc = fmaf(wa.w, ha.w, acc);
    acc = fmaf(wb.x, hb.x, acc);
    acc = fmaf(wb.y, hb.y, acc);
    acc = fmaf(wb.z, hb.z, acc);
    acc = fmaf(wb.w, hb.w, acc);
    return acc;
}

__device__ __forceinline__ float sigm(float x) { return 1.0f / (1.0f + expf(-x)); }

// ---------- persistent cooperative LSTM ----------
// grid: 256 blocks x 1024 threads = 4096 waves = one wave per hidden unit.
// (256x1024 is the R1-PROVEN cooperative-co-residable config; R2's 1024x256
// failed the co-residency check and silently never launched.)
// amdgpu_waves_per_eu(4,4): pin exactly 4 waves/EU (1 block/CU) so the
// register allocator gets the full 128-VGPR budget. R1's compiler chose
// 64 VGPRs (targeting 8 waves/EU) and spilled 174 MB/dispatch.
// Each wave owns gate rows {j, H+j, 2H+j, 3H+j}, keeps c[j] in registers.
// One grid.sync() per timestep (h double-buffered in d_ws).
template <bool BF16>
__global__ void
__attribute__((amdgpu_flat_work_group_size(1024, 1024), amdgpu_waves_per_eu(4, 4)))
lstm_kernel(const float* __restrict__ x,
            const float* __restrict__ w_ih,
            const float* __restrict__ b_ih,
            const float* __restrict__ b_hh,
            const void*  __restrict__ whh,
            const float* __restrict__ dense_w,
            const float* __restrict__ dense_b,
            float* __restrict__ h0,
            float* __restrict__ h1,
            float* __restrict__ out) {
    cg::grid_group grid = cg::this_grid();
    const int lane = threadIdx.x & 63;
    const int j = (blockIdx.x << 4) | (threadIdx.x >> 6);  // hidden unit, 0..4095

    // Per-gate constants for unit j (i, f, g, o rows)
    float wih0, wih1, wih2, wih3, bb0, bb1, bb2, bb3;
    wih0 = w_ih[0 * HID + j]; bb0 = b_ih[0 * HID + j] + b_hh[0 * HID + j];
    wih1 = w_ih[1 * HID + j]; bb1 = b_ih[1 * HID + j] + b_hh[1 * HID + j];
    wih2 = w_ih[2 * HID + j]; bb2 = b_ih[2 * HID + j] + b_hh[2 * HID + j];
    wih3 = w_ih[3 * HID + j]; bb3 = b_ih[3 * HID + j] + b_hh[3 * HID + j];

    if (lane == 0) h0[j] = 0.0f;
    float c = 0.0f;
    grid.sync();

    if constexpr (BF16) {
        const uint4* p0 = (const uint4*)((const unsigned short*)whh + (size_t)(0 * HID + j) * HID) + lane;
        const uint4* p1 = (const uint4*)((const unsigned short*)whh + (size_t)(1 * HID + j) * HID) + lane;
        const uint4* p2 = (const uint4*)((const unsigned short*)whh + (size_t)(2 * HID + j) * HID) + lane;
        const uint4* p3 = (const uint4*)((const unsigned short*)whh + (size_t)(3 * HID + j) * HID) + lane;

        for (int t = 0; t < SEQL; ++t) {
            const float4* hr = (const float4*)((t & 1) ? h1 : h0);
            float*        hw = (t & 1) ? h0 : h1;
            float xt = x[t];
            float acc0 = 0.f, acc1 = 0.f, acc2 = 0.f, acc3 = 0.f;

            // 2-stage software pipeline: next iteration's 6 loads issue while
            // current iteration's 32 FMAs run. Live load data ~80 VGPRs.
            uint4  w0 = p0[0], w1 = p1[0], w2 = p2[0], w3 = p3[0];
            float4 ha = hr[lane * 2], hb = hr[lane * 2 + 1];
#pragma unroll
            for (int it = 0; it < 8; ++it) {
                uint4  c0 = w0, c1 = w1, c2 = w2, c3 = w3;
                float4 cha = ha, chb = hb;
                if (it < 7) {
                    int ni = (it + 1) * 64;
                    w0 = p0[ni]; w1 = p1[ni]; w2 = p2[ni]; w3 = p3[ni];
                    ha = hr[(it + 1) * 128 + lane * 2];
                    hb = hr[(it + 1) * 128 + lane * 2 + 1];
                }
                acc0 = dot8_bf(c0, cha, chb, acc0);
                acc1 = dot8_bf(c1, cha, chb, acc1);
                acc2 = dot8_bf(c2, cha, chb, acc2);
                acc3 = dot8_bf(c3, cha, chb, acc3);
            }
#pragma unroll
            for (int off = 32; off; off >>= 1) {
                acc0 += __shfl_xor(acc0, off, 64);
                acc1 += __shfl_xor(acc1, off, 64);
                acc2 += __shfl_xor(acc2, off, 64);
                acc3 += __shfl_xor(acc3, off, 64);
            }
            float gi = acc0 + wih0 * xt + bb0;
            float gf = acc1 + wih1 * xt + bb1;
            float gg = acc2 + wih2 * xt + bb2;
            float go = acc3 + wih3 * xt + bb3;
            c = sigm(gf) * c + sigm(gi) * tanhf(gg);
            float hn = sigm(go) * tanhf(c);
            if (lane == 0) hw[j] = hn;
            grid.sync();
        }
    } else {
        const float4* q0 = (const float4*)((const float*)whh + (size_t)(0 * HID + j) * HID);
        const float4* q1 = (const float4*)((const float*)whh + (size_t)(1 * HID + j) * HID);
        const float4* q2 = (const float4*)((const float*)whh + (size_t)(2 * HID + j) * HID);
        const float4* q3 = (const float4*)((const float*)whh + (size_t)(3 * HID + j) * HID);
        for (int t = 0; t < SEQL; ++t) {
            const float4* hr = (const float4*)((t & 1) ? h1 : h0);
            float*        hw = (t & 1) ? h0 : h1;
            float xt = x[t];
            float acc0 = 0.f, acc1 = 0.f, acc2 = 0.f, acc3 = 0.f;
            for (int it = 0; it < 8; ++it) {
                int i0 = it * 128 + lane * 2;
                float4 ha = hr[i0], hb = hr[i0 + 1];
                acc0 = dot8_f32(q0[i0], q0[i0 + 1], ha, hb, acc0);
                acc1 = dot8_f32(q1[i0], q1[i0 + 1], ha, hb, acc1);
                acc2 = dot8_f32(q2[i0], q2[i0 + 1], ha, hb, acc2);
                acc3 = dot8_f32(q3[i0], q3[i0 + 1], ha, hb, acc3);
            }
#pragma unroll
            for (int off = 32; off; off >>= 1) {
                acc0 += __shfl_xor(acc0, off, 64);
                acc1 += __shfl_xor(acc1, off, 64);
                acc2 += __shfl_xor(acc2, off, 64);
                acc3 += __shfl_xor(acc3, off, 64);
            }
            float gi = acc0 + wih0 * xt + bb0;
            float gf = acc1 + wih1 * xt + bb1;
            float gg = acc2 + wih2 * xt + bb2;
            float go = acc3 + wih3 * xt + bb3;
            c = sigm(gf) * c + sigm(gi) * tanhf(gg);
            float hn = sigm(go) * tanhf(c);
            if (lane == 0) hw[j] = hn;
            grid.sync();
        }
    }

    // SEQL=40 even -> last write (t=39) went to h0.
    if (j < OUTN) {
        const float4* hv  = (const float4*)h0;
        const float4* dwr = (const float4*)(dense_w + (size_t)j * HID);
        float acc = 0.f;
#pragma unroll
        for (int it = 0; it < 8; ++it) {
            int i0 = it * 128 + lane * 2;
            float4 ha = hv[i0];
            float4 hb = hv[i0 + 1];
            acc = dot8_f32(dwr[i0], dwr[i0 + 1], ha, hb, acc);
        }
#pragma unroll
        for (int off = 32; off; off >>= 1) acc += __shfl_xor(acc, off, 64);
        if (lane == 0) out[j] = acc + dense_b[j];
    }
}

extern "C" void kernel_launch(void* const* d_in, const int* in_sizes, int n_in,
                              void* d_out, int out_size, void* d_ws, size_t ws_size,
                              hipStream_t stream) {
    const float* x       = (const float*)d_in[0];
    const float* w_ih    = (const float*)d_in[1];
    const float* w_hh    = (const float*)d_in[2];
    const float* b_ih    = (const float*)d_in[3];
    const float* b_hh    = (const float*)d_in[4];
    const float* dense_w = (const float*)d_in[5];
    const float* dense_b = (const float*)d_in[6];
    float* out = (float*)d_out;

    // ws layout: [h0: HID f32][h1: HID f32][w_hh as bf16: 4*HID*HID ushort]
    float* h0 = (float*)d_ws;
    float* h1 = h0 + HID;

    size_t need = (size_t)2 * HID * sizeof(float) +
                  (size_t)4 * HID * HID * sizeof(unsigned short);
    bool use_bf16 = ws_size >= need;

    if (use_bf16) {
        unsigned short* wbf = (unsigned short*)(h1 + HID);
        int n8 = 4 * HID * HID / 8;
        convert_w_kernel<<<2048, 256, 0, stream>>>((const float4*)w_hh, (uint4*)wbf, n8);

        const void* wptr = (const void*)wbf;
        void* args[] = {(void*)&x, (void*)&w_ih, (void*)&b_ih, (void*)&b_hh,
                        (void*)&wptr, (void*)&dense_w, (void*)&dense_b,
                        (void*)&h0, (void*)&h1, (void*)&out};
        void* fn = (void*)lstm_kernel<true>;
        hipLaunchCooperativeKernel(fn, dim3(256), dim3(1024), args, 0, stream);
    } else {
        const void* wptr = (const void*)w_hh;
        void* args[] = {(void*)&x, (void*)&w_ih, (void*)&b_ih, (void*)&b_hh,
                        (void*)&wptr, (void*)&dense_w, (void*)&dense_b,
                        (void*)&h0, (void*)&h1, (void*)&out};
        void* fn = (void*)lstm_kernel<false>;
        hipLaunchCooperativeKernel(fn, dim3(256), dim3(1024), args, 0, stream);
    }
}

// Round 4
// 2993.134 us; speedup vs baseline: 1.2191x; 1.2022x over previous
//
#include <hip/hip_runtime.h>

static constexpr int HID  = 4096;  // hidden size
static constexpr int SEQL = 40;
static constexpr int OUTN = 128;
static constexpr int NBLK = 256;   // 256 blocks x 1024 thr: R1/R3-proven co-residable

// ---------- fp32 -> bf16 (RNE) conversion ----------
__device__ __forceinline__ unsigned f2bf(float f) {
    unsigned u = __float_as_uint(f);
    return (u + 0x7fffu + ((u >> 16) & 1u)) >> 16;
}

__global__ void convert_w_kernel(const float4* __restrict__ w,
                                 uint4* __restrict__ o, int n8) {
    int stride = gridDim.x * blockDim.x;
    for (int i = blockIdx.x * blockDim.x + threadIdx.x; i < n8; i += stride) {
        float4 a = w[2 * i];
        float4 b = w[2 * i + 1];
        uint4 r;
        r.x = f2bf(a.x) | (f2bf(a.y) << 16);
        r.y = f2bf(a.z) | (f2bf(a.w) << 16);
        r.z = f2bf(b.x) | (f2bf(b.y) << 16);
        r.w = f2bf(b.z) | (f2bf(b.w) << 16);
        o[i] = r;
    }
}

// Zero h0|h1|ctr region (contiguous dwords at start of ws).
__global__ void init_ws_kernel(unsigned* __restrict__ p, int n) {
    int i = blockIdx.x * blockDim.x + threadIdx.x;
    if (i < n) p[i] = 0u;
}

// ---------- helpers ----------
__device__ __forceinline__ float bflo(unsigned u) { return __uint_as_float(u << 16); }
__device__ __forceinline__ float bfhi(unsigned u) { return __uint_as_float(u & 0xffff0000u); }

__device__ __forceinline__ float dot8_bf(uint4 w, float4 ha, float4 hb, float acc) {
    acc = fmaf(bflo(w.x), ha.x, acc);
    acc = fmaf(bfhi(w.x), ha.y, acc);
    acc = fmaf(bflo(w.y), ha.z, acc);
    acc = fmaf(bfhi(w.y), ha.w, acc);
    acc = fmaf(bflo(w.z), hb.x, acc);
    acc = fmaf(bfhi(w.z), hb.y, acc);
    acc = fmaf(bflo(w.w), hb.z, acc);
    acc = fmaf(bfhi(w.w), hb.w, acc);
    return acc;
}

__device__ __forceinline__ float dot8_f32(float4 wa, float4 wb, float4 ha, float4 hb, float acc) {
    acc = fmaf(wa.x, ha.x, acc);
    acc = fmaf(wa.y, ha.y, acc);
    acc = fmaf(wa.z, ha.z, acc);
    acc = fmaf(wa.w, ha.w, acc);
    acc = fmaf(wb.x, hb.x, acc);
    acc = fmaf(wb.y, hb.y, acc);
    acc = fmaf(wb.z, hb.z, acc);
    acc = fmaf(wb.w, hb.w, acc);
    return acc;
}

__device__ __forceinline__ float sigm(float x) { return 1.0f / (1.0f + expf(-x)); }

// Stage the 16KB h vector into LDS: each of 1024 threads pulls 4 floats via
// device-scope (MALL-coherent, L2-bypassing) atomic loads.
__device__ __forceinline__ void stage_h(float* __restrict__ hsh,
                                        const float* __restrict__ hsrc) {
    int base = threadIdx.x * 4;
    float4 v;
    v.x = __hip_atomic_load(hsrc + base + 0, __ATOMIC_RELAXED, __HIP_MEMORY_SCOPE_AGENT);
    v.y = __hip_atomic_load(hsrc + base + 1, __ATOMIC_RELAXED, __HIP_MEMORY_SCOPE_AGENT);
    v.z = __hip_atomic_load(hsrc + base + 2, __ATOMIC_RELAXED, __HIP_MEMORY_SCOPE_AGENT);
    v.w = __hip_atomic_load(hsrc + base + 3, __ATOMIC_RELAXED, __HIP_MEMORY_SCOPE_AGENT);
    *(float4*)(hsh + base) = v;
}

// ---------- persistent LSTM, hand-rolled MALL barrier (no grid.sync) ----------
// 256 blocks x 1024 threads = 4096 waves = one wave per hidden unit j.
// Cross-XCD h exchange + barrier counters go through device-scope atomics
// (coherent at MALL) -> no L2 writeback/invalidate per step, so the read-only
// bf16 weight stream stays cacheable in L2/L3 across all 40 steps.
template <bool BF16>
__global__ void
lstm_kernel(const float* __restrict__ x,
            const float* __restrict__ w_ih,
            const float* __restrict__ b_ih,
            const float* __restrict__ b_hh,
            const void*  __restrict__ whh,
            const float* __restrict__ dense_w,
            const float* __restrict__ dense_b,
            float* __restrict__ h0,
            float* __restrict__ h1,
            unsigned* __restrict__ ctr,
            float* __restrict__ out) {
    __shared__ float hsh[HID];  // 16 KB staged h
    const int lane = threadIdx.x & 63;
    const int j = (blockIdx.x << 4) | (threadIdx.x >> 6);  // hidden unit, 0..4095

    float wih0 = w_ih[0 * HID + j], bb0 = b_ih[0 * HID + j] + b_hh[0 * HID + j];
    float wih1 = w_ih[1 * HID + j], bb1 = b_ih[1 * HID + j] + b_hh[1 * HID + j];
    float wih2 = w_ih[2 * HID + j], bb2 = b_ih[2 * HID + j] + b_hh[2 * HID + j];
    float wih3 = w_ih[3 * HID + j], bb3 = b_ih[3 * HID + j] + b_hh[3 * HID + j];

    const uint4*  p0 = nullptr, *p1 = nullptr, *p2 = nullptr, *p3 = nullptr;
    const float4* q0 = nullptr, *q1 = nullptr, *q2 = nullptr, *q3 = nullptr;
    if constexpr (BF16) {
        p0 = (const uint4*)((const unsigned short*)whh + (size_t)(0 * HID + j) * HID);
        p1 = (const uint4*)((const unsigned short*)whh + (size_t)(1 * HID + j) * HID);
        p2 = (const uint4*)((const unsigned short*)whh + (size_t)(2 * HID + j) * HID);
        p3 = (const uint4*)((const unsigned short*)whh + (size_t)(3 * HID + j) * HID);
    } else {
        q0 = (const float4*)((const float*)whh + (size_t)(0 * HID + j) * HID);
        q1 = (const float4*)((const float*)whh + (size_t)(1 * HID + j) * HID);
        q2 = (const float4*)((const float*)whh + (size_t)(2 * HID + j) * HID);
        q3 = (const float4*)((const float*)whh + (size_t)(3 * HID + j) * HID);
    }

    float c = 0.0f;

    for (int t = 0; t < SEQL; ++t) {
        const float* hr = (t & 1) ? h1 : h0;   // t=0 reads h0 (zeros from init)
        float*       hw = (t & 1) ? h0 : h1;

        stage_h(hsh, hr);
        __syncthreads();

        const float4* hv = (const float4*)hsh;
        float xt = x[t];
        float acc0 = 0.f, acc1 = 0.f, acc2 = 0.f, acc3 = 0.f;

        if constexpr (BF16) {
            // depth-2 weight prefetch; h comes just-in-time from LDS.
            uint4 w0 = p0[lane], w1 = p1[lane], w2 = p2[lane], w3 = p3[lane];
#pragma unroll
            for (int it = 0; it < 8; ++it) {
                uint4 c0 = w0, c1 = w1, c2 = w2, c3 = w3;
                if (it < 7) {
                    int ni = (it + 1) * 64 + lane;
                    w0 = p0[ni]; w1 = p1[ni]; w2 = p2[ni]; w3 = p3[ni];
                }
                float4 ha = hv[it * 128 + lane * 2];
                float4 hb = hv[it * 128 + lane * 2 + 1];
                acc0 = dot8_bf(c0, ha, hb, acc0);
                acc1 = dot8_bf(c1, ha, hb, acc1);
                acc2 = dot8_bf(c2, ha, hb, acc2);
                acc3 = dot8_bf(c3, ha, hb, acc3);
            }
        } else {
#pragma unroll
            for (int it = 0; it < 8; ++it) {
                int i0 = it * 128 + lane * 2;
                float4 ha = hv[i0], hb = hv[i0 + 1];
                acc0 = dot8_f32(q0[i0], q0[i0 + 1], ha, hb, acc0);
                acc1 = dot8_f32(q1[i0], q1[i0 + 1], ha, hb, acc1);
                acc2 = dot8_f32(q2[i0], q2[i0 + 1], ha, hb, acc2);
                acc3 = dot8_f32(q3[i0], q3[i0 + 1], ha, hb, acc3);
            }
        }

#pragma unroll
        for (int off = 32; off; off >>= 1) {
            acc0 += __shfl_xor(acc0, off, 64);
            acc1 += __shfl_xor(acc1, off, 64);
            acc2 += __shfl_xor(acc2, off, 64);
            acc3 += __shfl_xor(acc3, off, 64);
        }
        float gi = acc0 + wih0 * xt + bb0;
        float gf = acc1 + wih1 * xt + bb1;
        float gg = acc2 + wih2 * xt + bb2;
        float go = acc3 + wih3 * xt + bb3;
        c = sigm(gf) * c + sigm(gi) * tanhf(gg);
        float hn = sigm(go) * tanhf(c);
        if (lane == 0)
            __hip_atomic_store(hw + j, hn, __ATOMIC_RELAXED, __HIP_MEMORY_SCOPE_AGENT);

        // ---- hand-rolled device barrier for step t ----
        // __syncthreads drains each wave's h-store (vmcnt(0) before s_barrier),
        // so one RELEASE add per block suffices; readers re-fetch h via
        // MALL-direct atomic loads, so no acquire/L2-invalidate is needed.
        __syncthreads();
        if (threadIdx.x == 0) {
            __hip_atomic_fetch_add(ctr + t, 1u, __ATOMIC_RELEASE, __HIP_MEMORY_SCOPE_AGENT);
            while (__hip_atomic_load(ctr + t, __ATOMIC_RELAXED, __HIP_MEMORY_SCOPE_AGENT)
                   < (unsigned)NBLK)
                __builtin_amdgcn_s_sleep(2);
        }
        __syncthreads();
    }

    // Final h is in h0 (t=39 odd wrote hw=h0). Dense epilogue on blocks 0-7.
    if (blockIdx.x < OUTN / 16) {
        stage_h(hsh, h0);
        __syncthreads();
        const float4* hv  = (const float4*)hsh;
        const float4* dwr = (const float4*)(dense_w + (size_t)j * HID);
        float acc = 0.f;
#pragma unroll
        for (int it = 0; it < 8; ++it) {
            int i0 = it * 128 + lane * 2;
            acc = dot8_f32(dwr[i0], dwr[i0 + 1], hv[i0], hv[i0 + 1], acc);
        }
#pragma unroll
        for (int off = 32; off; off >>= 1) acc += __shfl_xor(acc, off, 64);
        if (lane == 0) out[j] = acc + dense_b[j];
    }
}

extern "C" void kernel_launch(void* const* d_in, const int* in_sizes, int n_in,
                              void* d_out, int out_size, void* d_ws, size_t ws_size,
                              hipStream_t stream) {
    const float* x       = (const float*)d_in[0];
    const float* w_ih    = (const float*)d_in[1];
    const float* w_hh    = (const float*)d_in[2];
    const float* b_ih    = (const float*)d_in[3];
    const float* b_hh    = (const float*)d_in[4];
    const float* dense_w = (const float*)d_in[5];
    const float* dense_b = (const float*)d_in[6];
    float* out = (float*)d_out;

    // ws layout: h0[4096] f32 | h1[4096] f32 | ctr[64] u32 | wbf bf16[4*H*H]
    float*    h0  = (float*)d_ws;
    float*    h1  = h0 + HID;
    unsigned* ctr = (unsigned*)(h1 + HID);
    unsigned short* wbf = (unsigned short*)(ctr + 64);

    // Zero h0|h1|ctr (contiguous 2*HID + 64 dwords; harness poisons ws).
    int nz = 2 * HID + 64;
    init_ws_kernel<<<(nz + 1023) / 1024, 1024, 0, stream>>>((unsigned*)d_ws, nz);

    size_t need = (size_t)(2 * HID + 64) * 4 + (size_t)4 * HID * HID * sizeof(unsigned short);
    bool use_bf16 = ws_size >= need;

    if (use_bf16) {
        int n8 = 4 * HID * HID / 8;
        convert_w_kernel<<<2048, 256, 0, stream>>>((const float4*)w_hh, (uint4*)wbf, n8);
        const void* wptr = (const void*)wbf;
        void* args[] = {(void*)&x, (void*)&w_ih, (void*)&b_ih, (void*)&b_hh,
                        (void*)&wptr, (void*)&dense_w, (void*)&dense_b,
                        (void*)&h0, (void*)&h1, (void*)&ctr, (void*)&out};
        void* fn = (void*)lstm_kernel<true>;
        hipLaunchCooperativeKernel(fn, dim3(NBLK), dim3(1024), args, 0, stream);
    } else {
        const void* wptr = (const void*)w_hh;
        void* args[] = {(void*)&x, (void*)&w_ih, (void*)&b_ih, (void*)&b_hh,
                        (void*)&wptr, (void*)&dense_w, (void*)&dense_b,
                        (void*)&h0, (void*)&h1, (void*)&ctr, (void*)&out};
        void* fn = (void*)lstm_kernel<false>;
        hipLaunchCooperativeKernel(fn, dim3(NBLK), dim3(1024), args, 0, stream);
    }
}